// Round 1
// baseline (5710.984 us; speedup 1.0000x reference)
//
#include <hip/hip_runtime.h>
#include <stdint.h>

typedef short bf16x8 __attribute__((ext_vector_type(8)));
typedef float f32x4 __attribute__((ext_vector_type(4)));

__device__ __forceinline__ short f2bf(float f) {
    uint32_t u = __float_as_uint(f);
    u += 0x7fffu + ((u >> 16) & 1u);   // round-to-nearest-even
    return (short)(u >> 16);
}

// ---- weight f32 -> bf16 conversion (tiny, runs once per launch) ----
__global__ void convw_kernel(const float* __restrict__ in, short* __restrict__ out, int n) {
    int i = blockIdx.x * 256 + threadIdx.x;
    if (i < n) out[i] = f2bf(in[i]);
}

// ---- degree histogram (shared by both layers) ----
__global__ void deg_kernel(const int* __restrict__ dst, float* __restrict__ deg, int E) {
    int e = blockIdx.x * 256 + threadIdx.x;
    if (e < E) atomicAdd(&deg[dst[e]], 1.0f);
}

// ---- edge scatter: agg[dst] += xin[src], 32 threads (float4 each) per edge ----
__global__ void scatter_kernel(const float* __restrict__ xin, const int* __restrict__ src,
                               const int* __restrict__ dst, float* __restrict__ agg, int E) {
    int id = blockIdx.x * 256 + threadIdx.x;
    int e = id >> 5;
    int c = id & 31;
    if (e >= E) return;
    int s = src[e];
    int d = dst[e];
    const float4 v = *(const float4*)(xin + (size_t)s * 128 + c * 4);
    float* p = agg + (size_t)d * 128 + c * 4;
    atomicAdd(p + 0, v.x);
    atomicAdd(p + 1, v.y);
    atomicAdd(p + 2, v.z);
    atomicAdd(p + 3, v.w);
}

// ---- fused SAGE linear: out = [relu]( (agg/deg) @ Wl^T + b + xin @ Wr^T ) ----
// Wave tile: 16 nodes x 128 cols, K=256 (two A-sources of K=128 each).
// MFMA 16x16x32 bf16: A[m=lane&15][k=(lane>>4)*8+j]; B[k][n=lane&15] = W[n][k];
// C/D: col=lane&15, row=(lane>>4)*4+reg.
__global__ __launch_bounds__(256) void sage_gemm_kernel(
    const float* __restrict__ agg, const float* __restrict__ deg,
    const float* __restrict__ xin,
    const short* __restrict__ Wl, const short* __restrict__ Wr,
    const float* __restrict__ bias, float* __restrict__ out,
    int N, int relu)
{
    const int lane = threadIdx.x & 63;
    const int wave = threadIdx.x >> 6;
    const int m0   = blockIdx.x * 64 + wave * 16;
    const int mrow = m0 + (lane & 15);
    const int kq   = (lane >> 4) * 8;
    const bool valid = (mrow < N);

    float rdeg = 1.0f;
    if (valid) rdeg = 1.0f / fmaxf(deg[mrow], 1.0f);

    f32x4 acc[8];
#pragma unroll
    for (int i = 0; i < 8; ++i) acc[i] = (f32x4)0.0f;

    for (int s = 0; s < 2; ++s) {
        const float* __restrict__ A = s ? xin : agg;
        const short* __restrict__ W = s ? Wr : Wl;
        const float scale = s ? 1.0f : rdeg;
#pragma unroll
        for (int kk = 0; kk < 4; ++kk) {
            const int kb = kk * 32 + kq;
            bf16x8 a;
            if (valid) {
                const float4 v0 = *(const float4*)(A + (size_t)mrow * 128 + kb);
                const float4 v1 = *(const float4*)(A + (size_t)mrow * 128 + kb + 4);
                a[0] = f2bf(v0.x * scale); a[1] = f2bf(v0.y * scale);
                a[2] = f2bf(v0.z * scale); a[3] = f2bf(v0.w * scale);
                a[4] = f2bf(v1.x * scale); a[5] = f2bf(v1.y * scale);
                a[6] = f2bf(v1.z * scale); a[7] = f2bf(v1.w * scale);
            } else {
#pragma unroll
                for (int j = 0; j < 8; ++j) a[j] = 0;
            }
#pragma unroll
            for (int nt = 0; nt < 8; ++nt) {
                const bf16x8 b = *(const bf16x8*)(W + (size_t)(nt * 16 + (lane & 15)) * 128 + kb);
                acc[nt] = __builtin_amdgcn_mfma_f32_16x16x32_bf16(a, b, acc[nt], 0, 0, 0);
            }
        }
    }

    const int col0  = lane & 15;
    const int rbase = m0 + (lane >> 4) * 4;
#pragma unroll
    for (int nt = 0; nt < 8; ++nt) {
        const int col = nt * 16 + col0;
        const float bc = bias[col];
#pragma unroll
        for (int r = 0; r < 4; ++r) {
            const int node = rbase + r;
            if (node < N) {
                float v = acc[nt][r] + bc;
                if (relu) v = fmaxf(v, 0.0f);
                out[(size_t)node * 128 + col] = v;
            }
        }
    }
}

extern "C" void kernel_launch(void* const* d_in, const int* in_sizes, int n_in,
                              void* d_out, int out_size, void* d_ws, size_t ws_size,
                              hipStream_t stream) {
    const float* x   = (const float*)d_in[0];
    const int*   ei  = (const int*)d_in[1];
    const float* Wl1 = (const float*)d_in[2];
    const float* bl1 = (const float*)d_in[3];
    const float* Wr1 = (const float*)d_in[4];
    const float* Wl2 = (const float*)d_in[5];
    const float* bl2 = (const float*)d_in[6];
    const float* Wr2 = (const float*)d_in[7];

    const int N = in_sizes[0] / 128;
    const int E = in_sizes[1] / 2;
    const int* src = ei;
    const int* dst = ei + E;

    // workspace layout: h [N*128 f32] | deg [N f32] | 4x bf16 weights [16384 each]
    char* ws = (char*)d_ws;
    float* h   = (float*)ws;
    float* deg = (float*)(ws + (size_t)N * 128 * 4);
    short* wb  = (short*)(ws + (size_t)N * 128 * 4 + (size_t)N * 4);
    short* wl1 = wb;
    short* wr1 = wb + 16384;
    short* wl2 = wb + 32768;
    short* wr2 = wb + 49152;

    float* agg = (float*)d_out;  // agg lives in d_out for both layers
    float* out = (float*)d_out;

    const size_t featBytes = (size_t)N * 128 * sizeof(float);
    const int scatterBlocks = (int)(((size_t)E * 32 + 255) / 256);
    const int gemmBlocks = (N + 63) / 64;

    // layer 1
    hipMemsetAsync(agg, 0, featBytes, stream);
    hipMemsetAsync(deg, 0, (size_t)N * sizeof(float), stream);
    convw_kernel<<<64, 256, 0, stream>>>(Wl1, wl1, 16384);
    convw_kernel<<<64, 256, 0, stream>>>(Wr1, wr1, 16384);
    convw_kernel<<<64, 256, 0, stream>>>(Wl2, wl2, 16384);
    convw_kernel<<<64, 256, 0, stream>>>(Wr2, wr2, 16384);
    deg_kernel<<<(E + 255) / 256, 256, 0, stream>>>(dst, deg, E);
    scatter_kernel<<<scatterBlocks, 256, 0, stream>>>(x, src, dst, agg, E);
    sage_gemm_kernel<<<gemmBlocks, 256, 0, stream>>>(agg, deg, x, wl1, wr1, bl1, h, N, 1);

    // layer 2 (gemm is safely in-place on d_out: each wave reads/writes only its own rows)
    hipMemsetAsync(agg, 0, featBytes, stream);
    scatter_kernel<<<scatterBlocks, 256, 0, stream>>>(h, src, dst, agg, E);
    sage_gemm_kernel<<<gemmBlocks, 256, 0, stream>>>(agg, deg, h, wl2, wr2, bl2, out, N, 0);
}

// Round 3
// 591.718 us; speedup vs baseline: 9.6515x; 9.6515x over previous
//
#include <hip/hip_runtime.h>
#include <stdint.h>

typedef short bf16x8 __attribute__((ext_vector_type(8)));
typedef float f32x4 __attribute__((ext_vector_type(4)));

__device__ __forceinline__ short f2bf(float f) {
    uint32_t u = __float_as_uint(f);
    u += 0x7fffu + ((u >> 16) & 1u);   // round-to-nearest-even
    return (short)(u >> 16);
}
__device__ __forceinline__ float bf2f(unsigned short s) {
    return __uint_as_float((uint32_t)s << 16);
}

// ---- weight f32 -> bf16 (tiny) ----
__global__ void convw_kernel(const float* __restrict__ in, short* __restrict__ out, int n) {
    int i = blockIdx.x * 256 + threadIdx.x;
    if (i < n) out[i] = f2bf(in[i]);
}

// ---- histogram of dst into cnt (int atomics on 400KB, L2-resident) ----
__global__ void hist_kernel(const int* __restrict__ dst, int* __restrict__ cnt, int E) {
    int e = blockIdx.x * 256 + threadIdx.x;
    if (e < E) atomicAdd(&cnt[dst[e]], 1);
}

// ---- exclusive scan, 3 kernels: blockwise (1024 elem/block) -> partials -> add-back ----
__global__ void scan1_kernel(const int* __restrict__ cnt, int* __restrict__ rowptr,
                             int* __restrict__ partials, int N) {
    __shared__ int sdata[256];
    int t = threadIdx.x;
    int base = blockIdx.x * 1024 + t * 4;
    int v[4]; int s = 0;
#pragma unroll
    for (int j = 0; j < 4; ++j) {
        int idx = base + j;
        v[j] = (idx < N) ? cnt[idx] : 0;
        s += v[j];
    }
    sdata[t] = s;
    __syncthreads();
    for (int off = 1; off < 256; off <<= 1) {
        int add = (t >= off) ? sdata[t - off] : 0;
        __syncthreads();
        sdata[t] += add;
        __syncthreads();
    }
    if (t == 255) partials[blockIdx.x] = sdata[255];
    int run = sdata[t] - s;   // exclusive prefix of this thread's chunk
#pragma unroll
    for (int j = 0; j < 4; ++j) {
        int idx = base + j;
        if (idx < N) rowptr[idx] = run;
        run += v[j];
    }
}

__global__ void scan2_kernel(int* __restrict__ partials, int P) {
    __shared__ int sdata[128];
    int t = threadIdx.x;
    int v = (t < P) ? partials[t] : 0;
    sdata[t] = v;
    __syncthreads();
    for (int off = 1; off < 128; off <<= 1) {
        int add = (t >= off) ? sdata[t - off] : 0;
        __syncthreads();
        sdata[t] += add;
        __syncthreads();
    }
    if (t < P) partials[t] = sdata[t] - v;   // exclusive
}

__global__ void scan3_kernel(int* __restrict__ rowptr, const int* __restrict__ partials,
                             int N, int E) {
    int i = blockIdx.x * 256 + threadIdx.x;
    if (i < N) rowptr[i] += partials[i >> 10];
    if (i == 0) rowptr[N] = E;
}

// ---- counting-sort fill: csr[rowptr[d] + cursor[d]++] = src[e] ----
__global__ void fill_kernel(const int* __restrict__ src, const int* __restrict__ dst,
                            const int* __restrict__ rowptr, int* __restrict__ cnt,
                            int* __restrict__ csr, int E) {
    int e = blockIdx.x * 256 + threadIdx.x;
    if (e < E) {
        int d = dst[e];
        int pos = rowptr[d] + atomicAdd(&cnt[d], 1);
        csr[pos] = src[e];
    }
}

// ---- gather aggregation (f32 source): mean[node] = bf16( sum_{e} x[csr[e]] / deg ) ----
// one wave per node; lane l owns cols {2l, 2l+1}
__global__ __launch_bounds__(256) void agg_f32_kernel(
    const float* __restrict__ x, const int* __restrict__ csr,
    const int* __restrict__ rowptr, short* __restrict__ mean, int N) {
    int node = blockIdx.x * 4 + (threadIdx.x >> 6);
    if (node >= N) return;
    int lane = threadIdx.x & 63;
    int beg = rowptr[node], end = rowptr[node + 1];
    float ax = 0.f, ay = 0.f;
    int e = beg;
    for (; e + 4 <= end; e += 4) {
        int s0 = csr[e], s1 = csr[e + 1], s2 = csr[e + 2], s3 = csr[e + 3];
        float2 v0 = *(const float2*)(x + (size_t)s0 * 128 + lane * 2);
        float2 v1 = *(const float2*)(x + (size_t)s1 * 128 + lane * 2);
        float2 v2 = *(const float2*)(x + (size_t)s2 * 128 + lane * 2);
        float2 v3 = *(const float2*)(x + (size_t)s3 * 128 + lane * 2);
        ax += v0.x + v1.x + v2.x + v3.x;
        ay += v0.y + v1.y + v2.y + v3.y;
    }
    for (; e < end; ++e) {
        float2 v = *(const float2*)(x + (size_t)csr[e] * 128 + lane * 2);
        ax += v.x; ay += v.y;
    }
    float r = 1.0f / fmaxf((float)(end - beg), 1.0f);
    ushort2 o;
    o.x = (unsigned short)f2bf(ax * r);
    o.y = (unsigned short)f2bf(ay * r);
    *(ushort2*)(mean + (size_t)node * 128 + lane * 2) = o;
}

// ---- gather aggregation (bf16 source) ----
__global__ __launch_bounds__(256) void agg_bf16_kernel(
    const short* __restrict__ h, const int* __restrict__ csr,
    const int* __restrict__ rowptr, short* __restrict__ mean, int N) {
    int node = blockIdx.x * 4 + (threadIdx.x >> 6);
    if (node >= N) return;
    int lane = threadIdx.x & 63;
    int beg = rowptr[node], end = rowptr[node + 1];
    float ax = 0.f, ay = 0.f;
    int e = beg;
    for (; e + 4 <= end; e += 4) {
        int s0 = csr[e], s1 = csr[e + 1], s2 = csr[e + 2], s3 = csr[e + 3];
        ushort2 u0 = *(const ushort2*)(h + (size_t)s0 * 128 + lane * 2);
        ushort2 u1 = *(const ushort2*)(h + (size_t)s1 * 128 + lane * 2);
        ushort2 u2 = *(const ushort2*)(h + (size_t)s2 * 128 + lane * 2);
        ushort2 u3 = *(const ushort2*)(h + (size_t)s3 * 128 + lane * 2);
        ax += bf2f(u0.x) + bf2f(u1.x) + bf2f(u2.x) + bf2f(u3.x);
        ay += bf2f(u0.y) + bf2f(u1.y) + bf2f(u2.y) + bf2f(u3.y);
    }
    for (; e < end; ++e) {
        ushort2 u = *(const ushort2*)(h + (size_t)csr[e] * 128 + lane * 2);
        ax += bf2f(u.x); ay += bf2f(u.y);
    }
    float r = 1.0f / fmaxf((float)(end - beg), 1.0f);
    ushort2 o;
    o.x = (unsigned short)f2bf(ax * r);
    o.y = (unsigned short)f2bf(ay * r);
    *(ushort2*)(mean + (size_t)node * 128 + lane * 2) = o;
}

// ---- fused SAGE linear: out = [relu]( mean @ Wl^T + b + xin @ Wr^T ) ----
// L1=true: xin f32, out bf16 + relu. L1=false: xin bf16, out f32.
template <bool L1>
__global__ __launch_bounds__(256) void gemm_kernel(
    const short* __restrict__ mean,
    const float* __restrict__ xf, const short* __restrict__ xb,
    const short* __restrict__ Wl, const short* __restrict__ Wr,
    const float* __restrict__ bias,
    short* __restrict__ outb, float* __restrict__ outf, int N)
{
    const int lane = threadIdx.x & 63;
    const int wave = threadIdx.x >> 6;
    const int m0   = blockIdx.x * 64 + wave * 16;
    const int mrow = m0 + (lane & 15);
    const int kq   = (lane >> 4) * 8;
    const bool valid = (mrow < N);

    f32x4 acc[8];
#pragma unroll
    for (int i = 0; i < 8; ++i) acc[i] = (f32x4)0.0f;

    // source 0: mean (bf16, already scaled by 1/deg)
#pragma unroll
    for (int kk = 0; kk < 4; ++kk) {
        const int kb = kk * 32 + kq;
        bf16x8 a = (bf16x8)0;
        if (valid) a = *(const bf16x8*)(mean + (size_t)mrow * 128 + kb);
#pragma unroll
        for (int nt = 0; nt < 8; ++nt) {
            const bf16x8 b = *(const bf16x8*)(Wl + (size_t)(nt * 16 + (lane & 15)) * 128 + kb);
            acc[nt] = __builtin_amdgcn_mfma_f32_16x16x32_bf16(a, b, acc[nt], 0, 0, 0);
        }
    }
    // source 1: xin
#pragma unroll
    for (int kk = 0; kk < 4; ++kk) {
        const int kb = kk * 32 + kq;
        bf16x8 a = (bf16x8)0;
        if (valid) {
            if (L1) {
                const float4 v0 = *(const float4*)(xf + (size_t)mrow * 128 + kb);
                const float4 v1 = *(const float4*)(xf + (size_t)mrow * 128 + kb + 4);
                a[0] = f2bf(v0.x); a[1] = f2bf(v0.y); a[2] = f2bf(v0.z); a[3] = f2bf(v0.w);
                a[4] = f2bf(v1.x); a[5] = f2bf(v1.y); a[6] = f2bf(v1.z); a[7] = f2bf(v1.w);
            } else {
                a = *(const bf16x8*)(xb + (size_t)mrow * 128 + kb);
            }
        }
#pragma unroll
        for (int nt = 0; nt < 8; ++nt) {
            const bf16x8 b = *(const bf16x8*)(Wr + (size_t)(nt * 16 + (lane & 15)) * 128 + kb);
            acc[nt] = __builtin_amdgcn_mfma_f32_16x16x32_bf16(a, b, acc[nt], 0, 0, 0);
        }
    }

    const int col0  = lane & 15;
    const int rbase = m0 + (lane >> 4) * 4;
#pragma unroll
    for (int nt = 0; nt < 8; ++nt) {
        const int col = nt * 16 + col0;
        const float bc = bias[col];
#pragma unroll
        for (int r = 0; r < 4; ++r) {
            const int node = rbase + r;
            if (node < N) {
                float v = acc[nt][r] + bc;
                if (L1) outb[(size_t)node * 128 + col] = f2bf(fmaxf(v, 0.0f));
                else    outf[(size_t)node * 128 + col] = v;
            }
        }
    }
}

extern "C" void kernel_launch(void* const* d_in, const int* in_sizes, int n_in,
                              void* d_out, int out_size, void* d_ws, size_t ws_size,
                              hipStream_t stream) {
    const float* x   = (const float*)d_in[0];
    const int*   ei  = (const int*)d_in[1];
    const float* Wl1 = (const float*)d_in[2];
    const float* bl1 = (const float*)d_in[3];
    const float* Wr1 = (const float*)d_in[4];
    const float* Wl2 = (const float*)d_in[5];
    const float* bl2 = (const float*)d_in[6];
    const float* Wr2 = (const float*)d_in[7];

    const int N = in_sizes[0] / 128;
    const int E = in_sizes[1] / 2;
    const int* src = ei;
    const int* dst = ei + E;

    // ws: h_bf16 | mean_bf16 | 4x bf16 weights | scan partials  (~51.3 MB)
    short* hbuf = (short*)d_ws;
    short* mean = hbuf + (size_t)N * 128;
    short* wl1  = mean + (size_t)N * 128;
    short* wr1  = wl1 + 16384;
    short* wl2  = wr1 + 16384;
    short* wr2  = wl2 + 16384;
    int* partials = (int*)(wr2 + 16384);

    // d_out doubles as CSR scratch; final gemm overwrites it after all CSR readers
    int* rowptr = (int*)d_out;        // N+1
    int* cnt    = rowptr + (N + 1);   // N
    int* csr    = cnt + N;            // E
    float* out  = (float*)d_out;

    const int P = (N + 1023) >> 10;   // scan1 blocks (98 for N=100000, <=128)
    const int eBlocks = (E + 255) / 256;
    const int aggBlocks = (N + 3) / 4;
    const int gemmBlocks = (N + 63) / 64;

    convw_kernel<<<64, 256, 0, stream>>>(Wl1, wl1, 16384);
    convw_kernel<<<64, 256, 0, stream>>>(Wr1, wr1, 16384);
    convw_kernel<<<64, 256, 0, stream>>>(Wl2, wl2, 16384);
    convw_kernel<<<64, 256, 0, stream>>>(Wr2, wr2, 16384);

    // build CSR by destination
    (void)hipMemsetAsync(cnt, 0, (size_t)N * sizeof(int), stream);
    hist_kernel<<<eBlocks, 256, 0, stream>>>(dst, cnt, E);
    scan1_kernel<<<P, 256, 0, stream>>>(cnt, rowptr, partials, N);
    scan2_kernel<<<1, 128, 0, stream>>>(partials, P);
    scan3_kernel<<<(N + 255) / 256, 256, 0, stream>>>(rowptr, partials, N, E);
    (void)hipMemsetAsync(cnt, 0, (size_t)N * sizeof(int), stream);
    fill_kernel<<<eBlocks, 256, 0, stream>>>(src, dst, rowptr, cnt, csr, E);

    // layer 1
    agg_f32_kernel<<<aggBlocks, 256, 0, stream>>>(x, csr, rowptr, mean, N);
    gemm_kernel<true><<<gemmBlocks, 256, 0, stream>>>(mean, x, (const short*)nullptr,
                                                      wl1, wr1, bl1, hbuf, (float*)nullptr, N);
    // layer 2
    agg_bf16_kernel<<<aggBlocks, 256, 0, stream>>>(hbuf, csr, rowptr, mean, N);
    gemm_kernel<false><<<gemmBlocks, 256, 0, stream>>>(mean, (const float*)nullptr, hbuf,
                                                       wl2, wr2, bl2, (short*)nullptr, out, N);
}

// Round 4
// 562.152 us; speedup vs baseline: 10.1591x; 1.0526x over previous
//
#include <hip/hip_runtime.h>
#include <stdint.h>

typedef short bf16x8 __attribute__((ext_vector_type(8)));
typedef float f32x4 __attribute__((ext_vector_type(4)));

__device__ __forceinline__ short f2bf(float f) {
    uint32_t u = __float_as_uint(f);
    u += 0x7fffu + ((u >> 16) & 1u);   // round-to-nearest-even
    return (short)(u >> 16);
}
__device__ __forceinline__ float bf2f(unsigned short s) {
    return __uint_as_float((uint32_t)s << 16);
}

// ---- x f32 -> bf16, 8 elems/thread ----
__global__ __launch_bounds__(256) void convx_kernel(const float* __restrict__ in,
                                                    short* __restrict__ out, int n) {
    int i = (blockIdx.x * 256 + threadIdx.x) * 8;
    if (i + 8 <= n) {
        const float4 v0 = *(const float4*)(in + i);
        const float4 v1 = *(const float4*)(in + i + 4);
        bf16x8 o;
        o[0] = f2bf(v0.x); o[1] = f2bf(v0.y); o[2] = f2bf(v0.z); o[3] = f2bf(v0.w);
        o[4] = f2bf(v1.x); o[5] = f2bf(v1.y); o[6] = f2bf(v1.z); o[7] = f2bf(v1.w);
        *(bf16x8*)(out + i) = o;
    } else {
        for (int j = i; j < n; ++j) out[j] = f2bf(in[j]);
    }
}

// ---- all 4 weight matrices f32 -> bf16 in one launch (16384 elems each) ----
__global__ void convw4_kernel(const float* __restrict__ w0, const float* __restrict__ w1,
                              const float* __restrict__ w2, const float* __restrict__ w3,
                              short* __restrict__ o0, short* __restrict__ o1,
                              short* __restrict__ o2, short* __restrict__ o3) {
    int i = blockIdx.x * 256 + threadIdx.x;   // 16384 threads
    o0[i] = f2bf(w0[i]);
    o1[i] = f2bf(w1[i]);
    o2[i] = f2bf(w2[i]);
    o3[i] = f2bf(w3[i]);
}

// ---- histogram of dst (int atomics on 400KB, L2-resident) ----
__global__ void hist_kernel(const int* __restrict__ dst, int* __restrict__ cnt, int E) {
    int e = blockIdx.x * 256 + threadIdx.x;
    if (e < E) atomicAdd(&cnt[dst[e]], 1);
}

// ---- exclusive scan: blockwise (1024 elem/block) -> partials -> add-back ----
__global__ void scan1_kernel(const int* __restrict__ cnt, int* __restrict__ rowptr,
                             int* __restrict__ partials, int N) {
    __shared__ int sdata[256];
    int t = threadIdx.x;
    int base = blockIdx.x * 1024 + t * 4;
    int v[4]; int s = 0;
#pragma unroll
    for (int j = 0; j < 4; ++j) {
        int idx = base + j;
        v[j] = (idx < N) ? cnt[idx] : 0;
        s += v[j];
    }
    sdata[t] = s;
    __syncthreads();
    for (int off = 1; off < 256; off <<= 1) {
        int add = (t >= off) ? sdata[t - off] : 0;
        __syncthreads();
        sdata[t] += add;
        __syncthreads();
    }
    if (t == 255) partials[blockIdx.x] = sdata[255];
    int run = sdata[t] - s;
#pragma unroll
    for (int j = 0; j < 4; ++j) {
        int idx = base + j;
        if (idx < N) rowptr[idx] = run;
        run += v[j];
    }
}

__global__ void scan2_kernel(int* __restrict__ partials, int P) {
    __shared__ int sdata[128];
    int t = threadIdx.x;
    int v = (t < P) ? partials[t] : 0;
    sdata[t] = v;
    __syncthreads();
    for (int off = 1; off < 128; off <<= 1) {
        int add = (t >= off) ? sdata[t - off] : 0;
        __syncthreads();
        sdata[t] += add;
        __syncthreads();
    }
    if (t < P) partials[t] = sdata[t] - v;
}

__global__ void scan3_kernel(int* __restrict__ rowptr, const int* __restrict__ partials,
                             int N, int E) {
    int i = blockIdx.x * 256 + threadIdx.x;
    if (i < N) rowptr[i] += partials[i >> 10];
    if (i == 0) rowptr[N] = E;
}

// ---- counting-sort fill ----
__global__ void fill_kernel(const int* __restrict__ src, const int* __restrict__ dst,
                            const int* __restrict__ rowptr, int* __restrict__ cnt,
                            int* __restrict__ csr, int E) {
    int e = blockIdx.x * 256 + threadIdx.x;
    if (e < E) {
        int d = dst[e];
        int pos = rowptr[d] + atomicAdd(&cnt[d], 1);
        csr[pos] = src[e];
    }
}

// ---- bf16 gather-mean: one wave per node, two edges per iteration ----
// half-wave h reads edge e+h's row; lane covers 4 cols (ushort4 = 8B/lane);
// final cross-half reduce via shfl_xor(32).
__global__ __launch_bounds__(256) void agg_kernel(
    const short* __restrict__ feat, const int* __restrict__ csr,
    const int* __restrict__ rowptr, short* __restrict__ mean, int N) {
    int node = blockIdx.x * 4 + (threadIdx.x >> 6);
    if (node >= N) return;
    const int lane = threadIdx.x & 63;
    const int half = lane >> 5;
    const int c4   = (lane & 31) * 4;
    const int beg = rowptr[node], end = rowptr[node + 1];
    float a0 = 0.f, a1 = 0.f, a2 = 0.f, a3 = 0.f;
    int e = beg;
    for (; e + 4 <= end; e += 4) {
        int sa = csr[e + half];
        int sb = csr[e + 2 + half];
        ushort4 ua = *(const ushort4*)(feat + (size_t)sa * 128 + c4);
        ushort4 ub = *(const ushort4*)(feat + (size_t)sb * 128 + c4);
        a0 += bf2f(ua.x) + bf2f(ub.x);
        a1 += bf2f(ua.y) + bf2f(ub.y);
        a2 += bf2f(ua.z) + bf2f(ub.z);
        a3 += bf2f(ua.w) + bf2f(ub.w);
    }
    for (; e + 2 <= end; e += 2) {
        int s = csr[e + half];
        ushort4 u = *(const ushort4*)(feat + (size_t)s * 128 + c4);
        a0 += bf2f(u.x); a1 += bf2f(u.y); a2 += bf2f(u.z); a3 += bf2f(u.w);
    }
    if (e < end && half == 0) {
        int s = csr[e];
        ushort4 u = *(const ushort4*)(feat + (size_t)s * 128 + c4);
        a0 += bf2f(u.x); a1 += bf2f(u.y); a2 += bf2f(u.z); a3 += bf2f(u.w);
    }
    a0 += __shfl_xor(a0, 32);
    a1 += __shfl_xor(a1, 32);
    a2 += __shfl_xor(a2, 32);
    a3 += __shfl_xor(a3, 32);
    if (half == 0) {
        float r = 1.0f / fmaxf((float)(end - beg), 1.0f);
        ushort4 o;
        o.x = (unsigned short)f2bf(a0 * r);
        o.y = (unsigned short)f2bf(a1 * r);
        o.z = (unsigned short)f2bf(a2 * r);
        o.w = (unsigned short)f2bf(a3 * r);
        *(ushort4*)(mean + (size_t)node * 128 + c4) = o;
    }
}

// ---- fused SAGE linear: out = [relu]( mean @ Wl^T + b + xin @ Wr^T ), all-bf16 A ----
// RELU=true: bf16 out (layer 1). RELU=false: f32 out (layer 2).
template <bool RELU>
__global__ __launch_bounds__(256) void gemm_kernel(
    const short* __restrict__ mean, const short* __restrict__ xin,
    const short* __restrict__ Wl, const short* __restrict__ Wr,
    const float* __restrict__ bias,
    short* __restrict__ outb, float* __restrict__ outf, int N)
{
    const int lane = threadIdx.x & 63;
    const int wave = threadIdx.x >> 6;
    const int m0   = blockIdx.x * 64 + wave * 16;
    const int mrow = m0 + (lane & 15);
    const int kq   = (lane >> 4) * 8;
    const bool valid = (mrow < N);

    f32x4 acc[8];
#pragma unroll
    for (int i = 0; i < 8; ++i) acc[i] = (f32x4)0.0f;

#pragma unroll
    for (int kk = 0; kk < 4; ++kk) {
        const int kb = kk * 32 + kq;
        bf16x8 a = (bf16x8)0;
        if (valid) a = *(const bf16x8*)(mean + (size_t)mrow * 128 + kb);
#pragma unroll
        for (int nt = 0; nt < 8; ++nt) {
            const bf16x8 b = *(const bf16x8*)(Wl + (size_t)(nt * 16 + (lane & 15)) * 128 + kb);
            acc[nt] = __builtin_amdgcn_mfma_f32_16x16x32_bf16(a, b, acc[nt], 0, 0, 0);
        }
    }
#pragma unroll
    for (int kk = 0; kk < 4; ++kk) {
        const int kb = kk * 32 + kq;
        bf16x8 a = (bf16x8)0;
        if (valid) a = *(const bf16x8*)(xin + (size_t)mrow * 128 + kb);
#pragma unroll
        for (int nt = 0; nt < 8; ++nt) {
            const bf16x8 b = *(const bf16x8*)(Wr + (size_t)(nt * 16 + (lane & 15)) * 128 + kb);
            acc[nt] = __builtin_amdgcn_mfma_f32_16x16x32_bf16(a, b, acc[nt], 0, 0, 0);
        }
    }

    const int col0  = lane & 15;
    const int rbase = m0 + (lane >> 4) * 4;
#pragma unroll
    for (int nt = 0; nt < 8; ++nt) {
        const int col = nt * 16 + col0;
        const float bc = bias[col];
#pragma unroll
        for (int r = 0; r < 4; ++r) {
            const int node = rbase + r;
            if (node < N) {
                float v = acc[nt][r] + bc;
                if (RELU) outb[(size_t)node * 128 + col] = f2bf(fmaxf(v, 0.0f));
                else      outf[(size_t)node * 128 + col] = v;
            }
        }
    }
}

extern "C" void kernel_launch(void* const* d_in, const int* in_sizes, int n_in,
                              void* d_out, int out_size, void* d_ws, size_t ws_size,
                              hipStream_t stream) {
    const float* x   = (const float*)d_in[0];
    const int*   ei  = (const int*)d_in[1];
    const float* Wl1 = (const float*)d_in[2];
    const float* bl1 = (const float*)d_in[3];
    const float* Wr1 = (const float*)d_in[4];
    const float* Wl2 = (const float*)d_in[5];
    const float* bl2 = (const float*)d_in[6];
    const float* Wr2 = (const float*)d_in[7];

    const int N = in_sizes[0] / 128;
    const int E = in_sizes[1] / 2;
    const int* src = ei;
    const int* dst = ei + E;

    // ws: h_bf16 | mean_bf16 | 4x bf16 weights | scan partials  (~51.3 MB)
    short* hbuf = (short*)d_ws;
    short* mean = hbuf + (size_t)N * 128;
    short* wl1  = mean + (size_t)N * 128;
    short* wr1  = wl1 + 16384;
    short* wl2  = wr1 + 16384;
    short* wr2  = wl2 + 16384;
    int* partials = (int*)(wr2 + 16384);

    // d_out doubles as scratch: xb | rowptr | cnt | csr  (~32.8 MB of 51.2 MB).
    // gemm2 (the only other d_out writer) runs last and reads only ws.
    char* ob = (char*)d_out;
    short* xb   = (short*)ob;                                   // N*128 bf16
    size_t off  = (size_t)N * 128 * 2;
    int* rowptr = (int*)(ob + off);                             // N+1
    off += ((size_t)(N + 1) * 4 + 15) & ~(size_t)15;
    int* cnt    = (int*)(ob + off);                             // N
    off += ((size_t)N * 4 + 15) & ~(size_t)15;
    int* csr    = (int*)(ob + off);                             // E
    float* out  = (float*)d_out;

    const int P = (N + 1023) >> 10;   // <=128 for N<=131072
    const int eBlocks = (E + 255) / 256;
    const int aggBlocks = (N + 3) / 4;
    const int gemmBlocks = (N + 63) / 64;

    convx_kernel<<<(N * 128 / 8 + 255) / 256, 256, 0, stream>>>(x, xb, N * 128);
    convw4_kernel<<<64, 256, 0, stream>>>(Wl1, Wr1, Wl2, Wr2, wl1, wr1, wl2, wr2);

    // build CSR by destination
    (void)hipMemsetAsync(cnt, 0, (size_t)N * sizeof(int), stream);
    hist_kernel<<<eBlocks, 256, 0, stream>>>(dst, cnt, E);
    scan1_kernel<<<P, 256, 0, stream>>>(cnt, rowptr, partials, N);
    scan2_kernel<<<1, 128, 0, stream>>>(partials, P);
    scan3_kernel<<<(N + 255) / 256, 256, 0, stream>>>(rowptr, partials, N, E);
    (void)hipMemsetAsync(cnt, 0, (size_t)N * sizeof(int), stream);
    fill_kernel<<<eBlocks, 256, 0, stream>>>(src, dst, rowptr, cnt, csr, E);

    // layer 1
    agg_kernel<<<aggBlocks, 256, 0, stream>>>(xb, csr, rowptr, mean, N);
    gemm_kernel<true><<<gemmBlocks, 256, 0, stream>>>(mean, xb, wl1, wr1, bl1,
                                                      hbuf, (float*)nullptr, N);
    // layer 2
    agg_kernel<<<aggBlocks, 256, 0, stream>>>(hbuf, csr, rowptr, mean, N);
    gemm_kernel<false><<<gemmBlocks, 256, 0, stream>>>(mean, hbuf, wl2, wr2, bl2,
                                                       (short*)nullptr, out, N);
}

// Round 5
// 466.134 us; speedup vs baseline: 12.2518x; 1.2060x over previous
//
#include <hip/hip_runtime.h>
#include <stdint.h>

typedef short bf16x8 __attribute__((ext_vector_type(8)));
typedef float f32x4 __attribute__((ext_vector_type(4)));

#define NPB 512          // nodes per bucket
#define BSHIFT 9
#define MAXBUCK 256      // supports N <= 131072
#define STAGE_CAP 12288  // per-bucket csr staging (mean 8192, sigma ~90)

__device__ __forceinline__ short f2bf(float f) {
    uint32_t u = __float_as_uint(f);
    u += 0x7fffu + ((u >> 16) & 1u);   // round-to-nearest-even
    return (short)(u >> 16);
}
__device__ __forceinline__ float bf2f(unsigned short s) {
    return __uint_as_float((uint32_t)s << 16);
}

// ---- x f32 -> bf16, 8 elems/thread ----
__global__ __launch_bounds__(256) void convx_kernel(const float* __restrict__ in,
                                                    short* __restrict__ out, int n) {
    int i = (blockIdx.x * 256 + threadIdx.x) * 8;
    if (i + 8 <= n) {
        const float4 v0 = *(const float4*)(in + i);
        const float4 v1 = *(const float4*)(in + i + 4);
        bf16x8 o;
        o[0] = f2bf(v0.x); o[1] = f2bf(v0.y); o[2] = f2bf(v0.z); o[3] = f2bf(v0.w);
        o[4] = f2bf(v1.x); o[5] = f2bf(v1.y); o[6] = f2bf(v1.z); o[7] = f2bf(v1.w);
        *(bf16x8*)(out + i) = o;
    } else {
        for (int j = i; j < n; ++j) out[j] = f2bf(in[j]);
    }
}

// ---- all 4 weight matrices f32 -> bf16 in one launch ----
__global__ void convw4_kernel(const float* __restrict__ w0, const float* __restrict__ w1,
                              const float* __restrict__ w2, const float* __restrict__ w3,
                              short* __restrict__ o0, short* __restrict__ o1,
                              short* __restrict__ o2, short* __restrict__ o3) {
    int i = blockIdx.x * 256 + threadIdx.x;
    o0[i] = f2bf(w0[i]);
    o1[i] = f2bf(w1[i]);
    o2[i] = f2bf(w2[i]);
    o3[i] = f2bf(w3[i]);
}

// ---- coarse bucket histogram (LDS-aggregated) ----
__global__ __launch_bounds__(256) void bhist_kernel(const int* __restrict__ dst,
                                                    int* __restrict__ bcnt, int E, int B) {
    __shared__ int h[MAXBUCK];
    for (int i = threadIdx.x; i < B; i += 256) h[i] = 0;
    __syncthreads();
    int stride = gridDim.x * 256;
    for (int e = blockIdx.x * 256 + threadIdx.x; e < E; e += stride)
        atomicAdd(&h[dst[e] >> BSHIFT], 1);
    __syncthreads();
    for (int i = threadIdx.x; i < B; i += 256)
        if (h[i]) atomicAdd(&bcnt[i], h[i]);
}

// ---- scan bucket counts -> bases + init cursors; rowptr[N]=E ----
__global__ __launch_bounds__(256) void bscan_kernel(const int* __restrict__ bcnt,
                                                    int* __restrict__ bbase,
                                                    int* __restrict__ gcur,
                                                    int* __restrict__ rowptr,
                                                    int E, int N, int B) {
    __shared__ int s[256];
    int t = threadIdx.x;
    int v = (t < B) ? bcnt[t] : 0;
    s[t] = v;
    __syncthreads();
    for (int off = 1; off < 256; off <<= 1) {
        int a = (t >= off) ? s[t - off] : 0;
        __syncthreads();
        s[t] += a;
        __syncthreads();
    }
    int excl = s[t] - v;
    if (t < B) { bbase[t] = excl; gcur[t] = excl; }
    if (t == B - 1) bbase[B] = excl + v;
    if (t == 0) rowptr[N] = E;
}

// ---- bin edges into bucket regions as packed records (src<<9 | dst&511) ----
// per-wg LDS count -> one global atomic reservation per bucket -> contiguous runs
__global__ __launch_bounds__(256) void bin_kernel(const int* __restrict__ src,
                                                  const int* __restrict__ dst,
                                                  int* __restrict__ gcur,
                                                  unsigned int* __restrict__ binned,
                                                  int E, int B) {
    __shared__ int cnt[MAXBUCK];
    __shared__ int base[MAXBUCK];
    for (int i = threadIdx.x; i < B; i += 256) cnt[i] = 0;
    __syncthreads();
    const int e0 = blockIdx.x * 4096;
    int myS[16], myD[16];
    int n = 0;
#pragma unroll
    for (int i = 0; i < 16; ++i) {
        int e = e0 + threadIdx.x + i * 256;
        if (e < E) { myS[n] = src[e]; myD[n] = dst[e]; ++n; }
    }
    for (int i = 0; i < n; ++i) atomicAdd(&cnt[myD[i] >> BSHIFT], 1);
    __syncthreads();
    for (int i = threadIdx.x; i < B; i += 256) {
        int c = cnt[i];
        base[i] = c ? atomicAdd(&gcur[i], c) : 0;
        cnt[i] = 0;   // reuse as local cursor
    }
    __syncthreads();
    for (int i = 0; i < n; ++i) {
        int b = myD[i] >> BSHIFT;
        int off = atomicAdd(&cnt[b], 1);
        binned[base[b] + off] = ((unsigned)myS[i] << BSHIFT) | (unsigned)(myD[i] & (NPB - 1));
    }
}

// ---- per-bucket: local hist + scan -> rowptr; LDS scatter -> coalesced csr ----
__global__ __launch_bounds__(256) void build_kernel(const unsigned int* __restrict__ binned,
                                                    const int* __restrict__ bbase,
                                                    int* __restrict__ rowptr,
                                                    int* __restrict__ csr, int N) {
    __shared__ int hist[NPB];
    __shared__ int cur[NPB];
    __shared__ int scanb[256];
    __shared__ int stage[STAGE_CAP];
    const int b = blockIdx.x;
    const int t = threadIdx.x;
    const int cbeg = bbase[b], cend = bbase[b + 1];
    const int cnt = cend - cbeg;
    for (int i = t; i < NPB; i += 256) hist[i] = 0;
    __syncthreads();
    for (int i = t; i < cnt; i += 256)
        atomicAdd(&hist[binned[cbeg + i] & (NPB - 1)], 1);
    __syncthreads();
    // exclusive scan of 512 counts with 256 threads (2 per thread)
    const int h0 = hist[2 * t], h1 = hist[2 * t + 1];
    const int ps = h0 + h1;
    scanb[t] = ps;
    __syncthreads();
    for (int off = 1; off < 256; off <<= 1) {
        int a = (t >= off) ? scanb[t - off] : 0;
        __syncthreads();
        scanb[t] += a;
        __syncthreads();
    }
    const int e0 = scanb[t] - ps;
    cur[2 * t]     = e0;
    cur[2 * t + 1] = e0 + h0;
    __syncthreads();
    const int node0 = b << BSHIFT;
    for (int i = t; i < NPB; i += 256) {
        int node = node0 + i;
        if (node < N) rowptr[node] = cbeg + cur[i];
    }
    __syncthreads();   // rowptr reads of cur must finish before scatter mutates it
    for (int i = t; i < cnt; i += 256) {
        unsigned rec = binned[cbeg + i];
        int ld  = rec & (NPB - 1);
        int pos = atomicAdd(&cur[ld], 1);
        if (pos < STAGE_CAP) stage[pos] = (int)(rec >> BSHIFT);
        else                 csr[cbeg + pos] = (int)(rec >> BSHIFT);  // overflow safety
    }
    __syncthreads();
    const int lim = cnt < STAGE_CAP ? cnt : STAGE_CAP;
    for (int i = t; i < lim; i += 256)
        csr[cbeg + i] = stage[i];
}

// ---- bf16 gather-mean: one wave per node, two edges per iteration ----
__global__ __launch_bounds__(256) void agg_kernel(
    const short* __restrict__ feat, const int* __restrict__ csr,
    const int* __restrict__ rowptr, short* __restrict__ mean, int N) {
    int node = blockIdx.x * 4 + (threadIdx.x >> 6);
    if (node >= N) return;
    const int lane = threadIdx.x & 63;
    const int half = lane >> 5;
    const int c4   = (lane & 31) * 4;
    const int beg = rowptr[node], end = rowptr[node + 1];
    float a0 = 0.f, a1 = 0.f, a2 = 0.f, a3 = 0.f;
    int e = beg;
    for (; e + 4 <= end; e += 4) {
        int sa = csr[e + half];
        int sb = csr[e + 2 + half];
        ushort4 ua = *(const ushort4*)(feat + (size_t)sa * 128 + c4);
        ushort4 ub = *(const ushort4*)(feat + (size_t)sb * 128 + c4);
        a0 += bf2f(ua.x) + bf2f(ub.x);
        a1 += bf2f(ua.y) + bf2f(ub.y);
        a2 += bf2f(ua.z) + bf2f(ub.z);
        a3 += bf2f(ua.w) + bf2f(ub.w);
    }
    for (; e + 2 <= end; e += 2) {
        int s = csr[e + half];
        ushort4 u = *(const ushort4*)(feat + (size_t)s * 128 + c4);
        a0 += bf2f(u.x); a1 += bf2f(u.y); a2 += bf2f(u.z); a3 += bf2f(u.w);
    }
    if (e < end && half == 0) {
        int s = csr[e];
        ushort4 u = *(const ushort4*)(feat + (size_t)s * 128 + c4);
        a0 += bf2f(u.x); a1 += bf2f(u.y); a2 += bf2f(u.z); a3 += bf2f(u.w);
    }
    a0 += __shfl_xor(a0, 32);
    a1 += __shfl_xor(a1, 32);
    a2 += __shfl_xor(a2, 32);
    a3 += __shfl_xor(a3, 32);
    if (half == 0) {
        float r = 1.0f / fmaxf((float)(end - beg), 1.0f);
        ushort4 o;
        o.x = (unsigned short)f2bf(a0 * r);
        o.y = (unsigned short)f2bf(a1 * r);
        o.z = (unsigned short)f2bf(a2 * r);
        o.w = (unsigned short)f2bf(a3 * r);
        *(ushort4*)(mean + (size_t)node * 128 + c4) = o;
    }
}

// ---- fused SAGE linear: out = [relu]( mean @ Wl^T + b + xin @ Wr^T ) ----
template <bool RELU>
__global__ __launch_bounds__(256) void gemm_kernel(
    const short* __restrict__ mean, const short* __restrict__ xin,
    const short* __restrict__ Wl, const short* __restrict__ Wr,
    const float* __restrict__ bias,
    short* __restrict__ outb, float* __restrict__ outf, int N)
{
    const int lane = threadIdx.x & 63;
    const int wave = threadIdx.x >> 6;
    const int m0   = blockIdx.x * 64 + wave * 16;
    const int mrow = m0 + (lane & 15);
    const int kq   = (lane >> 4) * 8;
    const bool valid = (mrow < N);

    f32x4 acc[8];
#pragma unroll
    for (int i = 0; i < 8; ++i) acc[i] = (f32x4)0.0f;

#pragma unroll
    for (int kk = 0; kk < 4; ++kk) {
        const int kb = kk * 32 + kq;
        bf16x8 a = (bf16x8)0;
        if (valid) a = *(const bf16x8*)(mean + (size_t)mrow * 128 + kb);
#pragma unroll
        for (int nt = 0; nt < 8; ++nt) {
            const bf16x8 b = *(const bf16x8*)(Wl + (size_t)(nt * 16 + (lane & 15)) * 128 + kb);
            acc[nt] = __builtin_amdgcn_mfma_f32_16x16x32_bf16(a, b, acc[nt], 0, 0, 0);
        }
    }
#pragma unroll
    for (int kk = 0; kk < 4; ++kk) {
        const int kb = kk * 32 + kq;
        bf16x8 a = (bf16x8)0;
        if (valid) a = *(const bf16x8*)(xin + (size_t)mrow * 128 + kb);
#pragma unroll
        for (int nt = 0; nt < 8; ++nt) {
            const bf16x8 b = *(const bf16x8*)(Wr + (size_t)(nt * 16 + (lane & 15)) * 128 + kb);
            acc[nt] = __builtin_amdgcn_mfma_f32_16x16x32_bf16(a, b, acc[nt], 0, 0, 0);
        }
    }

    const int col0  = lane & 15;
    const int rbase = m0 + (lane >> 4) * 4;
#pragma unroll
    for (int nt = 0; nt < 8; ++nt) {
        const int col = nt * 16 + col0;
        const float bc = bias[col];
#pragma unroll
        for (int r = 0; r < 4; ++r) {
            const int node = rbase + r;
            if (node < N) {
                float v = acc[nt][r] + bc;
                if (RELU) outb[(size_t)node * 128 + col] = f2bf(fmaxf(v, 0.0f));
                else      outf[(size_t)node * 128 + col] = v;
            }
        }
    }
}

extern "C" void kernel_launch(void* const* d_in, const int* in_sizes, int n_in,
                              void* d_out, int out_size, void* d_ws, size_t ws_size,
                              hipStream_t stream) {
    const float* x   = (const float*)d_in[0];
    const int*   ei  = (const int*)d_in[1];
    const float* Wl1 = (const float*)d_in[2];
    const float* bl1 = (const float*)d_in[3];
    const float* Wr1 = (const float*)d_in[4];
    const float* Wl2 = (const float*)d_in[5];
    const float* bl2 = (const float*)d_in[6];
    const float* Wr2 = (const float*)d_in[7];

    const int N = in_sizes[0] / 128;
    const int E = in_sizes[1] / 2;
    const int* src = ei;
    const int* dst = ei + E;
    const int B = (N + NPB - 1) >> BSHIFT;   // 196 for N=100000

    // ws: h_bf16 | mean_bf16 | 4x bf16 weights  (~51.3 MB)
    short* hbuf = (short*)d_ws;
    short* mean = hbuf + (size_t)N * 128;
    short* wl1  = mean + (size_t)N * 128;
    short* wr1  = wl1 + 16384;
    short* wl2  = wr1 + 16384;
    short* wr2  = wl2 + 16384;

    // d_out doubles as scratch: xb | rowptr | csr | binned | bucket meta (~38.8 MB of 51.2).
    // gemm2 (the only final d_out writer) runs last and reads only ws.
    char* ob = (char*)d_out;
    short* xb = (short*)ob;                                     // N*128 bf16
    size_t off = (size_t)N * 128 * 2;
    int* rowptr = (int*)(ob + off);                             // N+1
    off += ((size_t)(N + 1) * 4 + 15) & ~(size_t)15;
    int* csr = (int*)(ob + off);                                // E
    off += ((size_t)E * 4 + 15) & ~(size_t)15;
    unsigned int* binned = (unsigned int*)(ob + off);           // E
    off += ((size_t)E * 4 + 15) & ~(size_t)15;
    int* bcnt  = (int*)(ob + off);                              // MAXBUCK+1
    int* bbase = bcnt + (MAXBUCK + 1);                          // MAXBUCK+1
    int* gcur  = bbase + (MAXBUCK + 1);                         // MAXBUCK
    float* out = (float*)d_out;

    const int aggBlocks  = (N + 3) / 4;
    const int gemmBlocks = (N + 63) / 64;
    const int binBlocks  = (E + 4095) / 4096;

    convx_kernel<<<(N * 128 / 8 + 255) / 256, 256, 0, stream>>>(x, xb, N * 128);
    convw4_kernel<<<64, 256, 0, stream>>>(Wl1, Wr1, Wl2, Wr2, wl1, wr1, wl2, wr2);

    // build CSR by destination (bucketed, coalesced)
    (void)hipMemsetAsync(bcnt, 0, (size_t)(MAXBUCK + 1) * sizeof(int), stream);
    bhist_kernel<<<256, 256, 0, stream>>>(dst, bcnt, E, B);
    bscan_kernel<<<1, 256, 0, stream>>>(bcnt, bbase, gcur, rowptr, E, N, B);
    bin_kernel<<<binBlocks, 256, 0, stream>>>(src, dst, gcur, binned, E, B);
    build_kernel<<<B, 256, 0, stream>>>(binned, bbase, rowptr, csr, N);

    // layer 1
    agg_kernel<<<aggBlocks, 256, 0, stream>>>(xb, csr, rowptr, mean, N);
    gemm_kernel<true><<<gemmBlocks, 256, 0, stream>>>(mean, xb, wl1, wr1, bl1,
                                                      hbuf, (float*)nullptr, N);
    // layer 2
    agg_kernel<<<aggBlocks, 256, 0, stream>>>(hbuf, csr, rowptr, mean, N);
    gemm_kernel<false><<<gemmBlocks, 256, 0, stream>>>(mean, hbuf, wl2, wr2, bl2,
                                                       (short*)nullptr, out, N);
}

// Round 6
// 432.894 us; speedup vs baseline: 13.1926x; 1.0768x over previous
//
#include <hip/hip_runtime.h>
#include <stdint.h>

typedef short bf16x8 __attribute__((ext_vector_type(8)));
typedef unsigned short u16x8 __attribute__((ext_vector_type(8)));
typedef float f32x4 __attribute__((ext_vector_type(4)));

#define NPB 512          // nodes per bucket
#define BSHIFT 9
#define MAXBUCK 256      // supports N <= 131072
#define STAGE_CAP 12288  // per-bucket csr staging (mean 8163, sigma ~90)
#define LROW 136         // LDS mean row stride in shorts (272 B)

__device__ __forceinline__ short f2bf(float f) {
    uint32_t u = __float_as_uint(f);
    u += 0x7fffu + ((u >> 16) & 1u);   // round-to-nearest-even
    return (short)(u >> 16);
}
__device__ __forceinline__ float bf2f(unsigned short s) {
    return __uint_as_float((uint32_t)s << 16);
}

// ---- x f32 -> bf16, 8 elems/thread ----
__global__ __launch_bounds__(256) void convx_kernel(const float* __restrict__ in,
                                                    short* __restrict__ out, int n) {
    int i = (blockIdx.x * 256 + threadIdx.x) * 8;
    if (i + 8 <= n) {
        const float4 v0 = *(const float4*)(in + i);
        const float4 v1 = *(const float4*)(in + i + 4);
        bf16x8 o;
        o[0] = f2bf(v0.x); o[1] = f2bf(v0.y); o[2] = f2bf(v0.z); o[3] = f2bf(v0.w);
        o[4] = f2bf(v1.x); o[5] = f2bf(v1.y); o[6] = f2bf(v1.z); o[7] = f2bf(v1.w);
        *(bf16x8*)(out + i) = o;
    } else {
        for (int j = i; j < n; ++j) out[j] = f2bf(in[j]);
    }
}

// ---- all 4 weight matrices f32 -> bf16 in one launch ----
__global__ void convw4_kernel(const float* __restrict__ w0, const float* __restrict__ w1,
                              const float* __restrict__ w2, const float* __restrict__ w3,
                              short* __restrict__ o0, short* __restrict__ o1,
                              short* __restrict__ o2, short* __restrict__ o3) {
    int i = blockIdx.x * 256 + threadIdx.x;
    o0[i] = f2bf(w0[i]);
    o1[i] = f2bf(w1[i]);
    o2[i] = f2bf(w2[i]);
    o3[i] = f2bf(w3[i]);
}

// ---- coarse bucket histogram (LDS-aggregated) ----
__global__ __launch_bounds__(256) void bhist_kernel(const int* __restrict__ dst,
                                                    int* __restrict__ bcnt, int E, int B) {
    __shared__ int h[MAXBUCK];
    for (int i = threadIdx.x; i < B; i += 256) h[i] = 0;
    __syncthreads();
    int stride = gridDim.x * 256;
    for (int e = blockIdx.x * 256 + threadIdx.x; e < E; e += stride)
        atomicAdd(&h[dst[e] >> BSHIFT], 1);
    __syncthreads();
    for (int i = threadIdx.x; i < B; i += 256)
        if (h[i]) atomicAdd(&bcnt[i], h[i]);
}

// ---- scan bucket counts -> bases + init cursors; rowptr[N]=E ----
__global__ __launch_bounds__(256) void bscan_kernel(const int* __restrict__ bcnt,
                                                    int* __restrict__ bbase,
                                                    int* __restrict__ gcur,
                                                    int* __restrict__ rowptr,
                                                    int E, int N, int B) {
    __shared__ int s[256];
    int t = threadIdx.x;
    int v = (t < B) ? bcnt[t] : 0;
    s[t] = v;
    __syncthreads();
    for (int off = 1; off < 256; off <<= 1) {
        int a = (t >= off) ? s[t - off] : 0;
        __syncthreads();
        s[t] += a;
        __syncthreads();
    }
    int excl = s[t] - v;
    if (t < B) { bbase[t] = excl; gcur[t] = excl; }
    if (t == B - 1) bbase[B] = excl + v;
    if (t == 0) rowptr[N] = E;
}

// ---- bin edges into bucket regions as packed records (src<<9 | dst&511) ----
__global__ __launch_bounds__(256) void bin_kernel(const int* __restrict__ src,
                                                  const int* __restrict__ dst,
                                                  int* __restrict__ gcur,
                                                  unsigned int* __restrict__ binned,
                                                  int E, int B) {
    __shared__ int cnt[MAXBUCK];
    __shared__ int base[MAXBUCK];
    for (int i = threadIdx.x; i < B; i += 256) cnt[i] = 0;
    __syncthreads();
    const int e0 = blockIdx.x * 4096;
    int myS[16], myD[16];
    int n = 0;
#pragma unroll
    for (int i = 0; i < 16; ++i) {
        int e = e0 + threadIdx.x + i * 256;
        if (e < E) { myS[n] = src[e]; myD[n] = dst[e]; ++n; }
    }
    for (int i = 0; i < n; ++i) atomicAdd(&cnt[myD[i] >> BSHIFT], 1);
    __syncthreads();
    for (int i = threadIdx.x; i < B; i += 256) {
        int c = cnt[i];
        base[i] = c ? atomicAdd(&gcur[i], c) : 0;
        cnt[i] = 0;   // reuse as local cursor
    }
    __syncthreads();
    for (int i = 0; i < n; ++i) {
        int b = myD[i] >> BSHIFT;
        int off = atomicAdd(&cnt[b], 1);
        binned[base[b] + off] = ((unsigned)myS[i] << BSHIFT) | (unsigned)(myD[i] & (NPB - 1));
    }
}

// ---- per-bucket: local hist + scan -> rowptr; LDS scatter -> coalesced csr ----
__global__ __launch_bounds__(256) void build_kernel(const unsigned int* __restrict__ binned,
                                                    const int* __restrict__ bbase,
                                                    int* __restrict__ rowptr,
                                                    int* __restrict__ csr, int N) {
    __shared__ int hist[NPB];
    __shared__ int cur[NPB];
    __shared__ int scanb[256];
    __shared__ int stage[STAGE_CAP];
    const int b = blockIdx.x;
    const int t = threadIdx.x;
    const int cbeg = bbase[b], cend = bbase[b + 1];
    const int cnt = cend - cbeg;
    for (int i = t; i < NPB; i += 256) hist[i] = 0;
    __syncthreads();
    for (int i = t; i < cnt; i += 256)
        atomicAdd(&hist[binned[cbeg + i] & (NPB - 1)], 1);
    __syncthreads();
    const int h0 = hist[2 * t], h1 = hist[2 * t + 1];
    const int ps = h0 + h1;
    scanb[t] = ps;
    __syncthreads();
    for (int off = 1; off < 256; off <<= 1) {
        int a = (t >= off) ? scanb[t - off] : 0;
        __syncthreads();
        scanb[t] += a;
        __syncthreads();
    }
    const int e0 = scanb[t] - ps;
    cur[2 * t]     = e0;
    cur[2 * t + 1] = e0 + h0;
    __syncthreads();
    const int node0 = b << BSHIFT;
    for (int i = t; i < NPB; i += 256) {
        int node = node0 + i;
        if (node < N) rowptr[node] = cbeg + cur[i];
    }
    __syncthreads();
    for (int i = t; i < cnt; i += 256) {
        unsigned rec = binned[cbeg + i];
        int ld  = rec & (NPB - 1);
        int pos = atomicAdd(&cur[ld], 1);
        if (pos < STAGE_CAP) stage[pos] = (int)(rec >> BSHIFT);
        else                 csr[cbeg + pos] = (int)(rec >> BSHIFT);
    }
    __syncthreads();
    const int lim = cnt < STAGE_CAP ? cnt : STAGE_CAP;
    for (int i = t; i < lim; i += 256)
        csr[cbeg + i] = stage[i];
}

// ---- fused layer: out = [relu]( mean(feat) @ Wl^T + b + feat @ Wr^T ) ----
// Block = 4 waves = 64 nodes. Wave w: (1) aggregate its 16 nodes, 4/iter via
// quarter-waves (full 256B row = 16 lanes x ushort8), mean -> LDS (bf16);
// (2) MFMA 16x128 tile, A(mean) from own LDS rows (no barrier), A(self) +
// B(weights) from global. Both layers' self-term input == gather source.
template <bool RELU>
__global__ __launch_bounds__(256) void fused_kernel(
    const short* __restrict__ feat, const int* __restrict__ csr,
    const int* __restrict__ rowptr,
    const short* __restrict__ Wl, const short* __restrict__ Wr,
    const float* __restrict__ bias,
    short* __restrict__ outb, float* __restrict__ outf, int N)
{
    __shared__ short lmean[64 * LROW];
    const int lane = threadIdx.x & 63;
    const int wave = threadIdx.x >> 6;
    const int q    = lane >> 4;          // quarter
    const int ql   = lane & 15;          // lane in quarter
    const int m0   = blockIdx.x * 64 + wave * 16;

    // ---- phase 1: aggregate; quarter q owns node m0 + it*4 + q
    for (int it = 0; it < 4; ++it) {
        const int node = m0 + it * 4 + q;
        float a0=0,a1=0,a2=0,a3=0,a4=0,a5=0,a6=0,a7=0;
        if (node < N) {
            const int beg = rowptr[node], end = rowptr[node + 1];
            int e = beg;
            for (; e + 4 <= end; e += 4) {
                const int s0 = csr[e], s1 = csr[e+1], s2 = csr[e+2], s3 = csr[e+3];
                u16x8 u0 = *(const u16x8*)(feat + (size_t)s0 * 128 + ql * 8);
                u16x8 u1 = *(const u16x8*)(feat + (size_t)s1 * 128 + ql * 8);
                u16x8 u2 = *(const u16x8*)(feat + (size_t)s2 * 128 + ql * 8);
                u16x8 u3 = *(const u16x8*)(feat + (size_t)s3 * 128 + ql * 8);
                a0 += bf2f(u0[0]) + bf2f(u1[0]) + bf2f(u2[0]) + bf2f(u3[0]);
                a1 += bf2f(u0[1]) + bf2f(u1[1]) + bf2f(u2[1]) + bf2f(u3[1]);
                a2 += bf2f(u0[2]) + bf2f(u1[2]) + bf2f(u2[2]) + bf2f(u3[2]);
                a3 += bf2f(u0[3]) + bf2f(u1[3]) + bf2f(u2[3]) + bf2f(u3[3]);
                a4 += bf2f(u0[4]) + bf2f(u1[4]) + bf2f(u2[4]) + bf2f(u3[4]);
                a5 += bf2f(u0[5]) + bf2f(u1[5]) + bf2f(u2[5]) + bf2f(u3[5]);
                a6 += bf2f(u0[6]) + bf2f(u1[6]) + bf2f(u2[6]) + bf2f(u3[6]);
                a7 += bf2f(u0[7]) + bf2f(u1[7]) + bf2f(u2[7]) + bf2f(u3[7]);
            }
            for (; e < end; ++e) {
                u16x8 u = *(const u16x8*)(feat + (size_t)csr[e] * 128 + ql * 8);
                a0 += bf2f(u[0]); a1 += bf2f(u[1]); a2 += bf2f(u[2]); a3 += bf2f(u[3]);
                a4 += bf2f(u[4]); a5 += bf2f(u[5]); a6 += bf2f(u[6]); a7 += bf2f(u[7]);
            }
            const float r = 1.0f / fmaxf((float)(end - beg), 1.0f);
            bf16x8 o;
            o[0] = f2bf(a0 * r); o[1] = f2bf(a1 * r); o[2] = f2bf(a2 * r); o[3] = f2bf(a3 * r);
            o[4] = f2bf(a4 * r); o[5] = f2bf(a5 * r); o[6] = f2bf(a6 * r); o[7] = f2bf(a7 * r);
            *(bf16x8*)(lmean + (size_t)(wave * 16 + it * 4 + q) * LROW + ql * 8) = o;
        }
    }
    // no __syncthreads: each wave reads only the 16 LDS rows it wrote

    // ---- phase 2: 16x128 MFMA tile
    f32x4 acc[8];
#pragma unroll
    for (int i = 0; i < 8; ++i) acc[i] = (f32x4)0.0f;
    const bool valid = (m0 + ql < N);

#pragma unroll
    for (int kk = 0; kk < 4; ++kk) {
        const int kb = kk * 32 + q * 8;
        const bf16x8 a = *(const bf16x8*)(lmean + (size_t)(wave * 16 + ql) * LROW + kb);
#pragma unroll
        for (int nt = 0; nt < 8; ++nt) {
            const bf16x8 b = *(const bf16x8*)(Wl + (size_t)(nt * 16 + ql) * 128 + kb);
            acc[nt] = __builtin_amdgcn_mfma_f32_16x16x32_bf16(a, b, acc[nt], 0, 0, 0);
        }
    }
#pragma unroll
    for (int kk = 0; kk < 4; ++kk) {
        const int kb = kk * 32 + q * 8;
        bf16x8 a = (bf16x8)0;
        if (valid) a = *(const bf16x8*)(feat + (size_t)(m0 + ql) * 128 + kb);
#pragma unroll
        for (int nt = 0; nt < 8; ++nt) {
            const bf16x8 b = *(const bf16x8*)(Wr + (size_t)(nt * 16 + ql) * 128 + kb);
            acc[nt] = __builtin_amdgcn_mfma_f32_16x16x32_bf16(a, b, acc[nt], 0, 0, 0);
        }
    }

    const int rbase = m0 + q * 4;
#pragma unroll
    for (int nt = 0; nt < 8; ++nt) {
        const int col = nt * 16 + ql;
        const float bc = bias[col];
#pragma unroll
        for (int r = 0; r < 4; ++r) {
            const int node = rbase + r;
            if (node < N) {
                float v = acc[nt][r] + bc;
                if (RELU) outb[(size_t)node * 128 + col] = f2bf(fmaxf(v, 0.0f));
                else      outf[(size_t)node * 128 + col] = v;
            }
        }
    }
}

extern "C" void kernel_launch(void* const* d_in, const int* in_sizes, int n_in,
                              void* d_out, int out_size, void* d_ws, size_t ws_size,
                              hipStream_t stream) {
    const float* x   = (const float*)d_in[0];
    const int*   ei  = (const int*)d_in[1];
    const float* Wl1 = (const float*)d_in[2];
    const float* bl1 = (const float*)d_in[3];
    const float* Wr1 = (const float*)d_in[4];
    const float* Wl2 = (const float*)d_in[5];
    const float* bl2 = (const float*)d_in[6];
    const float* Wr2 = (const float*)d_in[7];

    const int N = in_sizes[0] / 128;
    const int E = in_sizes[1] / 2;
    const int* src = ei;
    const int* dst = ei + E;
    const int B = (N + NPB - 1) >> BSHIFT;   // 196 for N=100000

    // ws: h_bf16 | 4x bf16 weights | rowptr | csr | binned | bucket meta (~39 MB)
    // (fused2 reads csr/rowptr while writing d_out, so CSR must live in ws)
    char* wsb = (char*)d_ws;
    short* hbuf = (short*)wsb;                                  // N*128 bf16
    size_t off = (size_t)N * 128 * 2;
    short* wl1 = (short*)(wsb + off); off += 16384 * 2;
    short* wr1 = (short*)(wsb + off); off += 16384 * 2;
    short* wl2 = (short*)(wsb + off); off += 16384 * 2;
    short* wr2 = (short*)(wsb + off); off += 16384 * 2;
    int* rowptr = (int*)(wsb + off);                            // N+1
    off += ((size_t)(N + 1) * 4 + 15) & ~(size_t)15;
    int* csr = (int*)(wsb + off);                               // E
    off += ((size_t)E * 4 + 15) & ~(size_t)15;
    unsigned int* binned = (unsigned int*)(wsb + off);          // E
    off += ((size_t)E * 4 + 15) & ~(size_t)15;
    int* bcnt  = (int*)(wsb + off);                             // MAXBUCK+1
    int* bbase = bcnt + (MAXBUCK + 1);                          // MAXBUCK+1
    int* gcur  = bbase + (MAXBUCK + 1);                         // MAXBUCK

    // d_out: xb (bf16 x) at base — read only by fused1, overwritten by fused2's out
    short* xb  = (short*)d_out;
    float* out = (float*)d_out;

    const int fusedBlocks = (N + 63) / 64;
    const int binBlocks   = (E + 4095) / 4096;

    convx_kernel<<<(N * 128 / 8 + 255) / 256, 256, 0, stream>>>(x, xb, N * 128);
    convw4_kernel<<<64, 256, 0, stream>>>(Wl1, Wr1, Wl2, Wr2, wl1, wr1, wl2, wr2);

    // build CSR by destination (bucketed, coalesced)
    (void)hipMemsetAsync(bcnt, 0, (size_t)(MAXBUCK + 1) * sizeof(int), stream);
    bhist_kernel<<<256, 256, 0, stream>>>(dst, bcnt, E, B);
    bscan_kernel<<<1, 256, 0, stream>>>(bcnt, bbase, gcur, rowptr, E, N, B);
    bin_kernel<<<binBlocks, 256, 0, stream>>>(src, dst, gcur, binned, E, B);
    build_kernel<<<B, 256, 0, stream>>>(binned, bbase, rowptr, csr, N);

    // layer 1: feat = xb (d_out), out = hbuf (ws)
    fused_kernel<true><<<fusedBlocks, 256, 0, stream>>>(xb, csr, rowptr, wl1, wr1, bl1,
                                                        hbuf, (float*)nullptr, N);
    // layer 2: feat = hbuf (ws), out = d_out (overwrites xb region; safe)
    fused_kernel<false><<<fusedBlocks, 256, 0, stream>>>(hbuf, csr, rowptr, wl2, wr2, bl2,
                                                         (short*)nullptr, out, N);
}